// Round 2
// baseline (178.970 us; speedup 1.0000x reference)
//
#include <hip/hip_runtime.h>

#define OUT 7
#define NCH 256
#define NROI 512
#define NS 14            // bilinear samples per axis (7 bins x 2)
#define NT 28            // tap slots per axis (lo/hi per sample)
#define CCH 16           // channels per block
#define W9 9             // LDS words per row-slot within a col-slot: 8 cp + 1 pad
#define WPC 253          // LDS words per col-slot: 28*9 + 1 (odd -> conflict-free)
#define TPR (NCH * OUT * OUT)

__device__ __forceinline__ float rfl_f(float v) {
    return __int_as_float(__builtin_amdgcn_readfirstlane(__float_as_int(v)));
}

// 8B load with only 4B alignment guarantee (col pair may start at odd col).
__device__ __forceinline__ float2 ld2(const float* p) {
    float2 r;
    __builtin_memcpy(&r, p, sizeof(float2));
    return r;
}

// D[15:0]=bf16(lo), D[31:16]=bf16(hi), RNE — matches the old manual round.
__device__ __forceinline__ unsigned int cvt_pk_bf16(float lo, float hi) {
    unsigned int r;
    asm("v_cvt_pk_bf16_f32 %0, %1, %2" : "=v"(r) : "v"(lo), "v"(hi));
    return r;
}

// Block = (RoI, 16-channel chunk). Phase 1: tap LUT (col PAIRS: base col +
// clamp-select). Phase 2: each lane = (sample 0..13, ch-quad 0..3); issues all
// 28 dwordx2 col-pair loads up front, then a sched_barrier(0) FORCES the
// scheduler to keep all 28 in flight (deep MLP) before the cvt/LDS-write
// region (compiler emits staged vmcnt(N) drains). Phase 3: 49 px x 8
// channel-pairs pooled from LDS. Phase 4: repack + float4 store.
// LDS word index: colslot*253 + rowslot*9 + cp  (cp = channel pair 0..7).
__global__ __launch_bounds__(256, 4) void roi_align_tap16_kernel(
        const float* __restrict__ f0, const float* __restrict__ f1,
        const float* __restrict__ f2, const float* __restrict__ f3,
        const float* __restrict__ boxes, float* __restrict__ out) {
    __shared__ __align__(16) unsigned short sm[NT * WPC * 2];  // 28,336 B
    __shared__ int   rowIdx[NT];
    __shared__ int   c0S[NS];      // base col of the (xl, xl+1) pair
    __shared__ int   selS[NS];     // 1 if xl clamped to H-1 (lo tap = hi value)
    __shared__ float lyS[NS], vyS[NS], lxS[NS], vxS[NS];

    int g    = blockIdx.x;
    int xcd  = g & 7;
    int slot = g >> 3;
    int rr   = slot >> 4;
    int q    = slot & 15;          // 16-channel chunk
    int r    = rr * 8 + xcd;       // RoI id: all 16 chunks share g%8 (same XCD)
    int tid  = (int)threadIdx.x;

    // ---------------- wave-uniform RoI meta ----------------
    float bx1 = rfl_f(boxes[r * 4 + 0]);
    float by1 = rfl_f(boxes[r * 4 + 1]);
    float bx2 = rfl_f(boxes[r * 4 + 2]);
    float by2 = rfl_f(boxes[r * 4 + 3]);

    float area = (bx2 - bx1) * (by2 - by1);
    float s    = sqrtf(area);
    float lvl  = floorf(4.0f + log2f(s * (1.0f / 224.0f) + 1e-6f));
    lvl        = fminf(fmaxf(lvl, 2.0f), 5.0f);
    int level  = __builtin_amdgcn_readfirstlane((int)lvl - 2);

    const float* f; int H; float scale;
    switch (level) {
        case 0:  f = f0; H = 200; scale = 0.25f;    break;
        case 1:  f = f1; H = 100; scale = 0.125f;   break;
        case 2:  f = f2; H = 50;  scale = 0.0625f;  break;
        default: f = f3; H = 25;  scale = 0.03125f; break;
    }
    float Hf = (float)H;

    float x1 = bx1 * scale, y1 = by1 * scale;
    float roi_w = fmaxf(bx2 * scale - x1, 1.0f);
    float roi_h = fmaxf(by2 * scale - y1, 1.0f);
    float bin_w = roi_w * (1.0f / OUT);
    float bin_h = roi_h * (1.0f / OUT);

    // ---------------- phase 1: tap LUT ----------------
    if (tid < NS) {                       // y samples
        int ph = tid >> 1, iy = tid & 1;
        float y = y1 + ((float)ph + (iy ? 0.75f : 0.25f)) * bin_h;
        float v = (y >= -1.0f && y <= Hf) ? 0.5f : 0.0f;   // vy*vx = 0.25
        y = fmaxf(y, 0.0f);
        int yl = (int)y, yh;
        float ly;
        if (yl >= H - 1) { yl = H - 1; yh = H - 1; ly = 0.0f; }
        else             { yh = yl + 1; ly = y - (float)yl; }
        lyS[tid] = ly; vyS[tid] = v;
        rowIdx[2 * tid]     = yl;
        rowIdx[2 * tid + 1] = yh;
    } else if (tid >= 32 && tid < 32 + NS) {   // x samples
        int t = tid - 32;
        int pw = t >> 1, ix = t & 1;
        float x = x1 + ((float)pw + (ix ? 0.75f : 0.25f)) * bin_w;
        float v = (x >= -1.0f && x <= Hf) ? 0.5f : 0.0f;
        x = fmaxf(x, 0.0f);
        int xl = (int)x;
        float lx; int c0, sel;
        if (xl >= H - 1) { c0 = H - 2; sel = 1; lx = 0.0f; }
        else             { c0 = xl;    sel = 0; lx = x - (float)xl; }
        lxS[t] = lx; vxS[t] = v;
        c0S[t] = c0; selS[t] = sel;
    }
    __syncthreads();

    // ---------------- phase 2: stage 28x28x16 tap grid ----------------
    int bidx = r >> 8;   // 256 RoIs per batch image
    size_t HH = (size_t)(H * H);
    const float* plane = f + (size_t)(bidx * NCH + q * CCH) * HH;

    int lane = tid & 63;
    int wave = tid >> 6;
    int cq   = lane / 14;  if (cq > 3) cq = 3;     // channel quad 0..3
    int sp   = lane - cq * 14;  if (sp > 13) sp = 13;  // x sample 0..13
    bool act = lane < 56;
    int  c0  = c0S[sp];
    bool sel = selS[sp] != 0;

    const float* base = plane + (size_t)(cq * 4) * HH;   // ch 4cq..4cq+3

    int roff[7];
#pragma unroll
    for (int t = 0; t < 7; ++t)
        roff[t] = rowIdx[wave * 7 + t] * H + c0;

    // issue ALL 28 col-pair loads; sched_barrier(0) pins them ABOVE the
    // convert region -> 28 loads in flight per wave (the whole point).
    float2 v[7][4];
#pragma unroll
    for (int t = 0; t < 7; ++t)
#pragma unroll
        for (int cc = 0; cc < 4; ++cc)
            v[t][cc] = ld2(base + (size_t)cc * HH + (size_t)roff[t]);
    __builtin_amdgcn_sched_barrier(0);

    unsigned int* smw_w = (unsigned int*)sm;
    int wbase = (2 * sp) * WPC + 2 * cq;
#pragma unroll
    for (int t = 0; t < 7; ++t) {
        int rs = wave * 7 + t;                     // row slot 0..27
        // lo tap value: clamped cols read (H-2,H-1) and both taps = f[H-1]
        float l0 = sel ? v[t][0].y : v[t][0].x;
        float l1 = sel ? v[t][1].y : v[t][1].x;
        float l2 = sel ? v[t][2].y : v[t][2].x;
        float l3 = sel ? v[t][3].y : v[t][3].x;
        unsigned int lo01 = cvt_pk_bf16(l0, l1);
        unsigned int lo23 = cvt_pk_bf16(l2, l3);
        unsigned int hi01 = cvt_pk_bf16(v[t][0].y, v[t][1].y);
        unsigned int hi23 = cvt_pk_bf16(v[t][2].y, v[t][3].y);
        if (act) {
            unsigned int* d0 = smw_w + wbase + rs * W9;
            d0[0]       = lo01;   // colslot 2sp,   cp 2cq
            d0[1]       = lo23;   // colslot 2sp,   cp 2cq+1
            d0[WPC]     = hi01;   // colslot 2sp+1, cp 2cq
            d0[WPC + 1] = hi23;   // colslot 2sp+1, cp 2cq+1
        }
    }
    __syncthreads();

    // ---------------- phase 3: pool 49 px x 8 channel-pairs ----------------
    const unsigned int* smw = (const unsigned int*)sm;
    float accx[2], accy[2];
#pragma unroll
    for (int i = 0; i < 2; ++i) { accx[i] = 0.0f; accy[i] = 0.0f; }

#pragma unroll
    for (int i = 0; i < 2; ++i) {
        int o = tid + 256 * i;
        if (o < 392) {
            int cp = o & 7, px = o >> 3;
            int ph = px / 7, pw = px - ph * 7;
            float ax = 0.0f, ay = 0.0f;
#pragma unroll
            for (int iy = 0; iy < 2; ++iy) {
                int sy = ph * 2 + iy;
                float ly = lyS[sy], hy = 1.0f - ly;
                float vy = vyS[sy];
                int r0 = (2 * sy) * W9 + cp;
                int r1 = r0 + W9;
#pragma unroll
                for (int ix = 0; ix < 2; ++ix) {
                    int sx = pw * 2 + ix;
                    float lx = lxS[sx], hx = 1.0f - lx;
                    float m  = vy * vxS[sx];       // 0.25 if valid else 0
                    int c0i = (2 * sx) * WPC;
                    int c1i = c0i + WPC;
                    unsigned int u00 = smw[c0i + r0];
                    unsigned int u01 = smw[c1i + r0];
                    unsigned int u10 = smw[c0i + r1];
                    unsigned int u11 = smw[c1i + r1];
                    float w00 = hy * hx * m, w01 = hy * lx * m;
                    float w10 = ly * hx * m, w11 = ly * lx * m;
                    ax = fmaf(w00, __uint_as_float(u00 << 16), ax);
                    ay = fmaf(w00, __uint_as_float(u00 & 0xFFFF0000u), ay);
                    ax = fmaf(w01, __uint_as_float(u01 << 16), ax);
                    ay = fmaf(w01, __uint_as_float(u01 & 0xFFFF0000u), ay);
                    ax = fmaf(w10, __uint_as_float(u10 << 16), ax);
                    ay = fmaf(w10, __uint_as_float(u10 & 0xFFFF0000u), ay);
                    ax = fmaf(w11, __uint_as_float(u11 << 16), ax);
                    ay = fmaf(w11, __uint_as_float(u11 & 0xFFFF0000u), ay);
                }
            }
            accx[i] = ax; accy[i] = ay;
        }
    }
    __syncthreads();   // LDS reads done; reuse sm for output repack

    // ---------------- phase 4: repack via LDS, contiguous float4 store ----------------
    float* smf = (float*)sm;
#pragma unroll
    for (int i = 0; i < 2; ++i) {
        int o = tid + 256 * i;
        if (o < 392) {
            int cp = o & 7, px = o >> 3;
            smf[(cp * 2 + 0) * 49 + px] = accx[i];  // even channel (low ushort)
            smf[(cp * 2 + 1) * 49 + px] = accy[i];  // odd channel (high ushort)
        }
    }
    __syncthreads();

    float* dst = out + (size_t)r * TPR + (size_t)q * (CCH * 49);
    if (tid < 196)
        ((float4*)dst)[tid] = ((const float4*)smf)[tid];
}

extern "C" void kernel_launch(void* const* d_in, const int* in_sizes, int n_in,
                              void* d_out, int out_size, void* d_ws, size_t ws_size,
                              hipStream_t stream) {
    const float* f0    = (const float*)d_in[0];
    const float* f1    = (const float*)d_in[1];
    const float* f2    = (const float*)d_in[2];
    const float* f3    = (const float*)d_in[3];
    const float* boxes = (const float*)d_in[4];
    float* out         = (float*)d_out;

    roi_align_tap16_kernel<<<NROI * 16, 256, 0, stream>>>(f0, f1, f2, f3, boxes, out);
}

// Round 3
// 178.850 us; speedup vs baseline: 1.0007x; 1.0007x over previous
//
#include <hip/hip_runtime.h>

#define OUT 7
#define NCH 256
#define NROI 512
#define NS 14            // bilinear samples per axis (7 bins x 2)
#define NT 28            // tap slots per axis (lo/hi per sample)
#define CCH 16           // channels per block
#define W9 9             // LDS words per row-slot within a col-slot: 8 cp + 1 pad
#define WPC 253          // LDS words per col-slot: 28*9 + 1 (odd -> conflict-free)
#define TPR (NCH * OUT * OUT)

__device__ __forceinline__ float rfl_f(float v) {
    return __int_as_float(__builtin_amdgcn_readfirstlane(__float_as_int(v)));
}

// 8B load with only 4B alignment guarantee (col pair may start at odd col).
__device__ __forceinline__ float2 ld2(const float* p) {
    float2 r;
    __builtin_memcpy(&r, p, sizeof(float2));
    return r;
}

// D[15:0]=bf16(lo), D[31:16]=bf16(hi), RNE — matches the old manual round.
__device__ __forceinline__ unsigned int cvt_pk_bf16(float lo, float hi) {
    unsigned int r;
    asm("v_cvt_pk_bf16_f32 %0, %1, %2" : "=v"(r) : "v"(lo), "v"(hi));
    return r;
}

// Block = (RoI, 16-channel chunk). Loads issue FIRST (addresses computed
// per-lane from the wave-uniform box, no LDS LUT dependency), pinned above
// the convert region by an IR-level memory fence (asm memory clobber) +
// sched_barrier -> all 28 col-pair loads in flight per lane (deep MLP).
// Weight LUT (phase 1) runs while loads are in flight. Phase 3: 49 px x 8
// channel-pairs pooled from LDS. Phase 4: repack + float4 store.
// LDS word index: colslot*253 + rowslot*9 + cp  (cp = channel pair 0..7).
__global__ __launch_bounds__(256, 4) void roi_align_tap16_kernel(
        const float* __restrict__ f0, const float* __restrict__ f1,
        const float* __restrict__ f2, const float* __restrict__ f3,
        const float* __restrict__ boxes, float* __restrict__ out) {
    __shared__ __align__(16) unsigned short sm[NT * WPC * 2];  // 28,336 B
    __shared__ float lyS[NS], vyS[NS], lxS[NS], vxS[NS];

    int g    = blockIdx.x;
    int xcd  = g & 7;
    int slot = g >> 3;
    int rr   = slot >> 4;
    int q    = slot & 15;          // 16-channel chunk
    int r    = rr * 8 + xcd;       // RoI id: all 16 chunks share g%8 (same XCD)
    int tid  = (int)threadIdx.x;

    // ---------------- wave-uniform RoI meta ----------------
    float bx1 = rfl_f(boxes[r * 4 + 0]);
    float by1 = rfl_f(boxes[r * 4 + 1]);
    float bx2 = rfl_f(boxes[r * 4 + 2]);
    float by2 = rfl_f(boxes[r * 4 + 3]);

    float area = (bx2 - bx1) * (by2 - by1);
    float s    = sqrtf(area);
    float lvl  = floorf(4.0f + log2f(s * (1.0f / 224.0f) + 1e-6f));
    lvl        = fminf(fmaxf(lvl, 2.0f), 5.0f);
    int level  = __builtin_amdgcn_readfirstlane((int)lvl - 2);

    const float* f; int H; float scale;
    switch (level) {
        case 0:  f = f0; H = 200; scale = 0.25f;    break;
        case 1:  f = f1; H = 100; scale = 0.125f;   break;
        case 2:  f = f2; H = 50;  scale = 0.0625f;  break;
        default: f = f3; H = 25;  scale = 0.03125f; break;
    }
    float Hf = (float)H;

    float x1 = bx1 * scale, y1 = by1 * scale;
    float roi_w = fmaxf(bx2 * scale - x1, 1.0f);
    float roi_h = fmaxf(by2 * scale - y1, 1.0f);
    float bin_w = roi_w * (1.0f / OUT);
    float bin_h = roi_h * (1.0f / OUT);

    // ---------------- phase 2a: per-lane tap addresses + ISSUE all loads ----
    int bidx = r >> 8;   // 256 RoIs per batch image
    size_t HH = (size_t)(H * H);
    const float* plane = f + (size_t)(bidx * NCH + q * CCH) * HH;

    int lane = tid & 63;
    int wave = tid >> 6;
    int cq   = lane / 14;  if (cq > 3) cq = 3;         // channel quad 0..3
    int sp   = lane - cq * 14;  if (sp > 13) sp = 13;  // x sample 0..13
    bool act = lane < 56;

    // col pair for this lane's x sample (bitwise-identical to weight-LUT math)
    int pw = sp >> 1, ixs = sp & 1;
    float xs = x1 + ((float)pw + (ixs ? 0.75f : 0.25f)) * bin_w;
    xs = fmaxf(xs, 0.0f);
    int xl = (int)xs;
    int c0; bool sel;
    if (xl >= H - 1) { c0 = H - 2; sel = true; }   // clamped: both taps = f[H-1]
    else             { c0 = xl;    sel = false; }

    // rows for this wave's 7 row-slots (slot rs -> y sample rs>>1, lo/hi rs&1)
    int roff[7];
#pragma unroll
    for (int t = 0; t < 7; ++t) {
        int rs = wave * 7 + t;
        int sy = rs >> 1;
        int ph = sy >> 1, iy = sy & 1;
        float ys = y1 + ((float)ph + (iy ? 0.75f : 0.25f)) * bin_h;
        ys = fmaxf(ys, 0.0f);
        int yl = (int)ys;
        int row = (yl >= H - 1) ? (H - 1) : (yl + (rs & 1));
        roff[t] = row * H + c0;
    }

    const float* base = plane + (size_t)(cq * 4) * HH;   // ch 4cq..4cq+3

    // issue ALL 28 col-pair loads, then an IR-level memory fence: loads
    // cannot sink past an asm memory clobber -> true 28-deep batch.
    float2 v[7][4];
#pragma unroll
    for (int t = 0; t < 7; ++t)
#pragma unroll
        for (int cc = 0; cc < 4; ++cc)
            v[t][cc] = ld2(base + (size_t)cc * HH + (size_t)roff[t]);
    asm volatile("" ::: "memory");
    __builtin_amdgcn_sched_barrier(0);

    // ---------------- phase 1 (overlapped): weight LUT ----------------
    if (tid < NS) {                       // y samples
        int ph = tid >> 1, iy = tid & 1;
        float y = y1 + ((float)ph + (iy ? 0.75f : 0.25f)) * bin_h;
        float vv = (y >= -1.0f && y <= Hf) ? 0.5f : 0.0f;   // vy*vx = 0.25
        y = fmaxf(y, 0.0f);
        int yl = (int)y;
        float ly = (yl >= H - 1) ? 0.0f : (y - (float)yl);
        lyS[tid] = ly; vyS[tid] = vv;
    } else if (tid >= 32 && tid < 32 + NS) {   // x samples
        int t = tid - 32;
        int pw2 = t >> 1, ix2 = t & 1;
        float x = x1 + ((float)pw2 + (ix2 ? 0.75f : 0.25f)) * bin_w;
        float vv = (x >= -1.0f && x <= Hf) ? 0.5f : 0.0f;
        x = fmaxf(x, 0.0f);
        int xl2 = (int)x;
        float lx = (xl2 >= H - 1) ? 0.0f : (x - (float)xl2);
        lxS[t] = lx; vxS[t] = vv;
    }

    // ---------------- phase 2b: convert + stage into LDS ----------------
    unsigned int* smw_w = (unsigned int*)sm;
    int wbase = (2 * sp) * WPC + 2 * cq;
#pragma unroll
    for (int t = 0; t < 7; ++t) {
        int rs = wave * 7 + t;                     // row slot 0..27
        // lo tap value: clamped cols read (H-2,H-1) and both taps = f[H-1]
        float l0 = sel ? v[t][0].y : v[t][0].x;
        float l1 = sel ? v[t][1].y : v[t][1].x;
        float l2 = sel ? v[t][2].y : v[t][2].x;
        float l3 = sel ? v[t][3].y : v[t][3].x;
        unsigned int lo01 = cvt_pk_bf16(l0, l1);
        unsigned int lo23 = cvt_pk_bf16(l2, l3);
        unsigned int hi01 = cvt_pk_bf16(v[t][0].y, v[t][1].y);
        unsigned int hi23 = cvt_pk_bf16(v[t][2].y, v[t][3].y);
        if (act) {
            unsigned int* d0 = smw_w + wbase + rs * W9;
            d0[0]       = lo01;   // colslot 2sp,   cp 2cq
            d0[1]       = lo23;   // colslot 2sp,   cp 2cq+1
            d0[WPC]     = hi01;   // colslot 2sp+1, cp 2cq
            d0[WPC + 1] = hi23;   // colslot 2sp+1, cp 2cq+1
        }
    }
    __syncthreads();

    // ---------------- phase 3: pool 49 px x 8 channel-pairs ----------------
    const unsigned int* smw = (const unsigned int*)sm;
    float accx[2], accy[2];
#pragma unroll
    for (int i = 0; i < 2; ++i) { accx[i] = 0.0f; accy[i] = 0.0f; }

#pragma unroll
    for (int i = 0; i < 2; ++i) {
        int o = tid + 256 * i;
        if (o < 392) {
            int cp = o & 7, px = o >> 3;
            int ph = px / 7, pw2 = px - ph * 7;
            float ax = 0.0f, ay = 0.0f;
#pragma unroll
            for (int iy = 0; iy < 2; ++iy) {
                int sy = ph * 2 + iy;
                float ly = lyS[sy], hy = 1.0f - ly;
                float vy = vyS[sy];
                int r0 = (2 * sy) * W9 + cp;
                int r1 = r0 + W9;
#pragma unroll
                for (int ix = 0; ix < 2; ++ix) {
                    int sx = pw2 * 2 + ix;
                    float lx = lxS[sx], hx = 1.0f - lx;
                    float m  = vy * vxS[sx];       // 0.25 if valid else 0
                    int c0i = (2 * sx) * WPC;
                    int c1i = c0i + WPC;
                    unsigned int u00 = smw[c0i + r0];
                    unsigned int u01 = smw[c1i + r0];
                    unsigned int u10 = smw[c0i + r1];
                    unsigned int u11 = smw[c1i + r1];
                    float w00 = hy * hx * m, w01 = hy * lx * m;
                    float w10 = ly * hx * m, w11 = ly * lx * m;
                    ax = fmaf(w00, __uint_as_float(u00 << 16), ax);
                    ay = fmaf(w00, __uint_as_float(u00 & 0xFFFF0000u), ay);
                    ax = fmaf(w01, __uint_as_float(u01 << 16), ax);
                    ay = fmaf(w01, __uint_as_float(u01 & 0xFFFF0000u), ay);
                    ax = fmaf(w10, __uint_as_float(u10 << 16), ax);
                    ay = fmaf(w10, __uint_as_float(u10 & 0xFFFF0000u), ay);
                    ax = fmaf(w11, __uint_as_float(u11 << 16), ax);
                    ay = fmaf(w11, __uint_as_float(u11 & 0xFFFF0000u), ay);
                }
            }
            accx[i] = ax; accy[i] = ay;
        }
    }
    __syncthreads();   // LDS reads done; reuse sm for output repack

    // ---------------- phase 4: repack via LDS, contiguous float4 store ----------------
    float* smf = (float*)sm;
#pragma unroll
    for (int i = 0; i < 2; ++i) {
        int o = tid + 256 * i;
        if (o < 392) {
            int cp = o & 7, px = o >> 3;
            smf[(cp * 2 + 0) * 49 + px] = accx[i];  // even channel (low ushort)
            smf[(cp * 2 + 1) * 49 + px] = accy[i];  // odd channel (high ushort)
        }
    }
    __syncthreads();

    float* dst = out + (size_t)r * TPR + (size_t)q * (CCH * 49);
    if (tid < 196)
        ((float4*)dst)[tid] = ((const float4*)smf)[tid];
}

extern "C" void kernel_launch(void* const* d_in, const int* in_sizes, int n_in,
                              void* d_out, int out_size, void* d_ws, size_t ws_size,
                              hipStream_t stream) {
    const float* f0    = (const float*)d_in[0];
    const float* f1    = (const float*)d_in[1];
    const float* f2    = (const float*)d_in[2];
    const float* f3    = (const float*)d_in[3];
    const float* boxes = (const float*)d_in[4];
    float* out         = (float*)d_out;

    roi_align_tap16_kernel<<<NROI * 16, 256, 0, stream>>>(f0, f1, f2, f3, boxes, out);
}